// Round 7
// baseline (745.606 us; speedup 1.0000x reference)
//
#include <hip/hip_runtime.h>
#include <math.h>

#define BATCH 2048
#define SEQ   128
#define HID   512
#define OUTT  24
#define RPB   16              // batch rows per block (MFMA M)
#define NBLK  (BATCH/RPB)     // 128 blocks
#define TPB   512             // 8 waves = 2/SIMD
#define NTW   4               // n-tiles per wave
#define KTN   (HID/32)        // 16 k-tiles
#define NTILES (HID/16)       // 32 n-tiles
#define HOLD_KT 8             // k-tiles held in registers (128 VGPR/lane)
#define STR_KT  (KTN - HOLD_KT)

typedef _Float16 half8 __attribute__((ext_vector_type(8)));
typedef float   floatx4 __attribute__((ext_vector_type(4)));

// fast tanh: 1 - 2/(e^{2x}+1), e^{2x} = 2^(x*2/ln2). Saturates correctly.
__device__ __forceinline__ float ftanh(float x) {
    float e = __builtin_amdgcn_exp2f(x * 2.885390081777927f);
    float r = __builtin_amdgcn_rcpf(e + 1.0f);
    return fmaf(-2.0f, r, 1.0f);
}

// Pack W[j][k] (row-major HIDxHID fp32) into per-lane MFMA B-fragment layout,
// fp16: frag[(kt*32+nt)*64 + lane][8]; lane holds
// B[k = kt*32 + (lane>>4)*8 + jj][n = nt*16 + (lane&15)] = W[n][k].
__global__ __launch_bounds__(256) void pack_wfrag(const float* __restrict__ W,
                                                  _Float16* __restrict__ Bw)
{
    int id   = blockIdx.x * 256 + threadIdx.x;
    int lane = id & 63;
    int nt   = (id >> 6) & 31;
    int kt   = id >> 11;
    int n  = nt * 16 + (lane & 15);
    int k0 = kt * 32 + (lane >> 4) * 8;
    const float* src = W + (size_t)n * HID + k0;
    half8 v;
    #pragma unroll
    for (int j = 0; j < 8; j++) v[j] = (_Float16)src[j];
    *(half8*)&Bw[(size_t)id * 8] = v;
}

// Swizzled A layout: el(m,k) = (k>>5)*512 + G*128 + ((m^G)<<3) + (k&7), G=(k>>3)&3.
// Reader lane (q,c), k-tile kt: contiguous aligned 16 B at kt*512 + q*128 + ((c^q)<<3).
__global__ __attribute__((amdgpu_flat_work_group_size(TPB, TPB),
                          amdgpu_waves_per_eu(2, 2)))
void rnn_persist(
    const float* __restrict__ x,
    const _Float16* __restrict__ BwE,
    const _Float16* __restrict__ BwD,
    const float* __restrict__ encWih, const float* __restrict__ encBih,
    const float* __restrict__ encBhh,
    const float* __restrict__ decWih, const float* __restrict__ decBih,
    const float* __restrict__ decBhh,
    const float* __restrict__ fcW, const float* __restrict__ fcB,
    float* __restrict__ out)
{
    __shared__ _Float16 Ahi[2][KTN * 512];   // 2 x 16 KB
    __shared__ _Float16 Alo[2][KTN * 512];   // 2 x 16 KB
    __shared__ float    xs[RPB][SEQ];        // 8 KB
    __shared__ float    dec_in_s[RPB];

    const int tid  = threadIdx.x;
    const int lane = tid & 63;
    const int wv   = tid >> 6;
    const int row0 = blockIdx.x * RPB;
    const int c    = lane & 15;
    const int q    = lane >> 4;
    const int mB   = q * 4;

    // epilogue constants per owned n
    float eWi[NTW], eBb[NTW], dWi[NTW], dBb[NTW];
    #pragma unroll
    for (int i = 0; i < NTW; i++) {
        int n = (wv * NTW + i) * 16 + c;
        eWi[i] = encWih[n]; eBb[i] = encBih[n] + encBhh[n];
        dWi[i] = decWih[n]; dBb[i] = decBih[n] + decBhh[n];
    }
    const float fcb0 = fcB[0];

    // preload x block-slice into LDS (coalesced float4)
    {
        const float4* xg = (const float4*)(x + (size_t)row0 * SEQ);
        float4* xl = (float4*)&xs[0][0];
        if (tid < RPB * SEQ / 4) xl[tid] = xg[tid];
    }

    // h0 = 0
    for (int i = tid; i < KTN * 512 / 2; i += TPB) {
        ((int*)Ahi[0])[i] = 0;
        ((int*)Alo[0])[i] = 0;
    }
    __syncthreads();

    const int ldsAoff = q * 128 + ((c ^ q) << 3);
    const size_t bbase = (size_t)(wv * NTW) * 512 + (size_t)lane * 8;

    // ---- load held weight k-tiles into registers (encoder first) ----
    half8 wreg[HOLD_KT][NTW];
    #pragma unroll
    for (int kt = 0; kt < HOLD_KT; kt++)
        #pragma unroll
        for (int i = 0; i < NTW; i++)
            wreg[kt][i] = *(const half8*)&BwE[bbase + (size_t)kt * 16384 + i * 512];

    int cur = 0;
    for (int t = 0; t < SEQ + OUTT; t++) {
        const bool enc = (t < SEQ);
        const _Float16* __restrict__ Bw = enc ? BwE : BwD;
        const _Float16* Ah = Ahi[cur];
        const _Float16* Al = Alo[cur];

        if (t == SEQ) {   // one-time: swap held weights to decoder matrix
            #pragma unroll
            for (int kt = 0; kt < HOLD_KT; kt++)
                #pragma unroll
                for (int i = 0; i < NTW; i++)
                    wreg[kt][i] = *(const half8*)&BwD[bbase + (size_t)kt * 16384 + i * 512];
        }

        floatx4 acc[NTW];
        #pragma unroll
        for (int i = 0; i < NTW; i++) acc[i] = (floatx4){0.f, 0.f, 0.f, 0.f};

        // prime streamed-B prefetch (2 k-tiles deep) before held compute
        half8 bcur[NTW], bnxt[NTW];
        #pragma unroll
        for (int i = 0; i < NTW; i++) {
            bcur[i] = *(const half8*)&Bw[bbase + (size_t)HOLD_KT * 16384 + i * 512];
            bnxt[i] = *(const half8*)&Bw[bbase + (size_t)(HOLD_KT + 1) * 16384 + i * 512];
        }

        // held k-tiles: B from registers, zero memory traffic
        #pragma unroll
        for (int kt = 0; kt < HOLD_KT; kt++) {
            half8 ah = *(const half8*)&Ah[kt * 512 + ldsAoff];
            half8 al = *(const half8*)&Al[kt * 512 + ldsAoff];
            #pragma unroll
            for (int i = 0; i < NTW; i++)
                acc[i] = __builtin_amdgcn_mfma_f32_16x16x32_f16(ah, wreg[kt][i], acc[i], 0, 0, 0);
            #pragma unroll
            for (int i = 0; i < NTW; i++)
                acc[i] = __builtin_amdgcn_mfma_f32_16x16x32_f16(al, wreg[kt][i], acc[i], 0, 0, 0);
        }

        // streamed k-tiles with rolling 2-deep prefetch
        #pragma unroll
        for (int s = 0; s < STR_KT; s++) {
            const int kt = HOLD_KT + s;
            half8 bpre[NTW];
            if (s + 2 < STR_KT) {
                #pragma unroll
                for (int i = 0; i < NTW; i++)
                    bpre[i] = *(const half8*)&Bw[bbase + (size_t)(kt + 2) * 16384 + i * 512];
            }
            half8 ah = *(const half8*)&Ah[kt * 512 + ldsAoff];
            half8 al = *(const half8*)&Al[kt * 512 + ldsAoff];
            #pragma unroll
            for (int i = 0; i < NTW; i++)
                acc[i] = __builtin_amdgcn_mfma_f32_16x16x32_f16(ah, bcur[i], acc[i], 0, 0, 0);
            #pragma unroll
            for (int i = 0; i < NTW; i++)
                acc[i] = __builtin_amdgcn_mfma_f32_16x16x32_f16(al, bcur[i], acc[i], 0, 0, 0);
            #pragma unroll
            for (int i = 0; i < NTW; i++) {
                bcur[i] = bnxt[i];
                if (s + 2 < STR_KT) bnxt[i] = bpre[i];
            }
        }

        // ---- epilogue ----
        float inp[4];
        if (enc) {
            #pragma unroll
            for (int r = 0; r < 4; r++) inp[r] = xs[mB + r][t];
        } else if (t == SEQ) {
            #pragma unroll
            for (int r = 0; r < 4; r++) inp[r] = xs[mB + r][SEQ - 1];
        } else {
            #pragma unroll
            for (int r = 0; r < 4; r++) inp[r] = dec_in_s[mB + r];
        }

        const int nxt = cur ^ 1;
        #pragma unroll
        for (int i = 0; i < NTW; i++) {
            int nt = wv * NTW + i;
            int k  = nt * 16 + c;            // this n is next step's k
            int G  = (k >> 3) & 3;
            int base = (k >> 5) * 512 + G * 128 + (k & 7);
            float wi = enc ? eWi[i] : dWi[i];
            float bb = enc ? eBb[i] : dBb[i];
            #pragma unroll
            for (int r = 0; r < 4; r++) {
                float v = ftanh(acc[i][r] + inp[r] * wi + bb);
                _Float16 hh = (_Float16)v;
                float rs = v - (float)hh;
                int off = base + (((mB + r) ^ G) << 3);
                Ahi[nxt][off] = hh;
                Alo[nxt][off] = (_Float16)rs;
            }
        }
        __syncthreads();   // A[nxt] complete

        if (!enc) {
            // FC: wave wv reduces rows 2wv, 2wv+1
            #pragma unroll
            for (int rr = 0; rr < 2; rr++) {
                int m = wv * 2 + rr;
                float s = 0.f;
                #pragma unroll
                for (int ii = 0; ii < HID / 64; ii++) {
                    int k = ii * 64 + lane;
                    int G = (k >> 3) & 3;
                    int a = (k >> 5) * 512 + G * 128 + ((m ^ G) << 3) + (k & 7);
                    float hvv = (float)Ahi[nxt][a] + (float)Alo[nxt][a];
                    s = fmaf(hvv, fcW[k], s);
                }
                #pragma unroll
                for (int off = 32; off > 0; off >>= 1)
                    s += __shfl_down(s, off, 64);
                if (lane == 0) {
                    float o = s + fcb0;
                    dec_in_s[m] = o;
                    out[(size_t)(row0 + m) * OUTT + (t - SEQ)] = o;
                }
            }
            __syncthreads();
        }
        cur = nxt;
    }
}

extern "C" void kernel_launch(void* const* d_in, const int* in_sizes, int n_in,
                              void* d_out, int out_size, void* d_ws, size_t ws_size,
                              hipStream_t stream)
{
    const float* x        = (const float*)d_in[0];
    const float* enc_Wih  = (const float*)d_in[1];
    const float* enc_Whh  = (const float*)d_in[2];
    const float* enc_bih  = (const float*)d_in[3];
    const float* enc_bhh  = (const float*)d_in[4];
    const float* dec_Wih  = (const float*)d_in[5];
    const float* dec_Whh  = (const float*)d_in[6];
    const float* dec_bih  = (const float*)d_in[7];
    const float* dec_bhh  = (const float*)d_in[8];
    const float* fc_W     = (const float*)d_in[9];
    const float* fc_b     = (const float*)d_in[10];
    float* out = (float*)d_out;

    const size_t wfrag = (size_t)HID * HID;
    _Float16* BwE = (_Float16*)d_ws;
    _Float16* BwD = BwE + wfrag;

    pack_wfrag<<<HID * HID / (256 * 8), 256, 0, stream>>>(enc_Whh, BwE);
    pack_wfrag<<<HID * HID / (256 * 8), 256, 0, stream>>>(dec_Whh, BwD);

    rnn_persist<<<NBLK, TPB, 0, stream>>>(
        x, BwE, BwD,
        enc_Wih, enc_bih, enc_bhh,
        dec_Wih, dec_bih, dec_bhh,
        fc_W, fc_b, out);
}